// Round 2
// baseline (5015.734 us; speedup 1.0000x reference)
//
#include <hip/hip_runtime.h>
#include <hip/hip_cooperative_groups.h>
#include <math.h>

namespace cg = cooperative_groups;

#define C    1536
#define MA   1536
#define NWG  256
#define TPB  384              // 6 waves per block -> 1536 waves = one per row
#define NTH  (NWG * TPB)

// workspace layout (float indices)
#define WS_H0   0             // [C]
#define WS_H1   (C)           // [C]
#define WS_HIDA (2*C)         // [3*C]
#define WS_HIDB (5*C)         // [3*C]
#define WS_C    (8*C)         // int: step count c

__device__ __forceinline__ float wave_reduce(float v) {
#pragma unroll
    for (int off = 32; off > 0; off >>= 1) v += __shfl_xor(v, off, 64);
    return v;
}

// one 1536-dot spread over a 64-lane wave, float4 loads
__device__ __forceinline__ float dot_row64(const float* __restrict__ W,
                                           const float* __restrict__ v, int lane) {
    const float4* W4 = (const float4*)W;
    const float4* v4 = (const float4*)v;
    float acc = 0.f;
#pragma unroll
    for (int j = 0; j < C / 256; ++j) {          // 6 iters
        float4 a = W4[lane + 64 * j];
        float4 b = v4[lane + 64 * j];
        acc = fmaf(a.x, b.x, acc); acc = fmaf(a.y, b.y, acc);
        acc = fmaf(a.z, b.z, acc); acc = fmaf(a.w, b.w, acc);
    }
    return acc;
}

// fused pair of 1536-dots (W_ih row · cur  +  W_hh row · hid)
__device__ __forceinline__ float dot2_row64(const float* __restrict__ Wa,
                                            const float* __restrict__ va,
                                            const float* __restrict__ Wb,
                                            const float* __restrict__ vb, int lane) {
    const float4* Wa4 = (const float4*)Wa;
    const float4* va4 = (const float4*)va;
    const float4* Wb4 = (const float4*)Wb;
    const float4* vb4 = (const float4*)vb;
    float acc0 = 0.f, acc1 = 0.f;
#pragma unroll
    for (int j = 0; j < C / 256; ++j) {
        float4 a = Wa4[lane + 64 * j];
        float4 b = va4[lane + 64 * j];
        acc0 = fmaf(a.x, b.x, acc0); acc0 = fmaf(a.y, b.y, acc0);
        acc0 = fmaf(a.z, b.z, acc0); acc0 = fmaf(a.w, b.w, acc0);
        float4 e = Wb4[lane + 64 * j];
        float4 f = vb4[lane + 64 * j];
        acc1 = fmaf(e.x, f.x, acc1); acc1 = fmaf(e.y, f.y, acc1);
        acc1 = fmaf(e.z, f.z, acc1); acc1 = fmaf(e.w, f.w, acc1);
    }
    return acc0 + acc1;
}

__global__ void __launch_bounds__(TPB, 1)
ve_main(const float* __restrict__ x,
        const float* __restrict__ lw0, const float* __restrict__ lb0,
        const float* __restrict__ lw1, const float* __restrict__ lb1,
        const float* __restrict__ lw2, const float* __restrict__ lb2,
        const float* __restrict__ Wih, const float* __restrict__ bih,
        const float* __restrict__ Whh, const float* __restrict__ bhh,
        float* __restrict__ out, float* __restrict__ wsf) {
    cg::grid_group grid = cg::this_grid();
    int* wsi = (int*)wsf;
    const int tid  = threadIdx.x;
    const int wg   = blockIdx.x;
    const int wave = tid >> 6;
    const int lane = tid & 63;
    const int row  = wg * 6 + wave;          // one wave per output row, 0..1535
    const int gtid = wg * TPB + tid;

    // zero full seq region of d_out (rows >= c must be 0; buffer is poisoned)
    float4 z4 = make_float4(0.f, 0.f, 0.f, 0.f);
    float4* out4 = (float4*)out;
#pragma unroll
    for (int i = 0; i < 6; ++i) out4[(size_t)i * NTH + gtid] = z4;

    // init hid = [x, 0, 0]  (inp0 == hid0[2] == 0, so inp==hid[2] invariant holds)
    if (gtid < C) {
        wsf[WS_HIDA + gtid]         = x[gtid];
        wsf[WS_HIDA + C + gtid]     = 0.f;
        wsf[WS_HIDA + 2 * C + gtid] = 0.f;
    }

    // ---- MLP layer 0: h0 = leaky_relu(lw0 @ x + lb0) ----
    {
        float acc = wave_reduce(dot_row64(lw0 + (size_t)row * C, x, lane));
        if (lane == 0) {
            float v = acc + lb0[row];
            wsf[WS_H0 + row] = (v > 0.f) ? v : 0.2f * v;
        }
    }
    grid.sync();

    // ---- MLP layer 1: h1 = leaky_relu(lw1 @ h0 + lb1) ----
    {
        float acc = wave_reduce(dot_row64(lw1 + (size_t)row * C, wsf + WS_H0, lane));
        if (lane == 0) {
            float v = acc + lb1[row];
            wsf[WS_H1 + row] = (v > 0.f) ? v : 0.2f * v;
        }
    }
    grid.sync();

    // ---- head: l = lw2 · h1 + lb2 ; length ; c ----
    if (wg == 0 && wave == 0) {
        float acc = wave_reduce(dot_row64(lw2, wsf + WS_H1, lane));
        if (lane == 0) {
            float l = acc + lb2[0];
            float length = fminf(fabsf(l), 0.9999f);
            out[(size_t)MA * C] = length;                  // output 1
            wsi[WS_C] = (int)floorf(length * (float)MA) + 1;
        }
    }
    grid.sync();
    const int csteps = wsi[WS_C];

    // ---- RNN: c timesteps, 3 stacked layers each ----
    float* hid_old = wsf + WS_HIDA;   // [x, 0, 0] initially
    float* hid_new = wsf + WS_HIDB;
    for (int t = 0; t < csteps; ++t) {
#pragma unroll
        for (int l = 0; l < 3; ++l) {
            // layer-0 input is prev timestep's layer-2 output == hid_old[2]
            const float* curv = (l == 0) ? (hid_old + 2 * C) : (hid_new + (l - 1) * C);
            const float* hl   = hid_old + l * C;
            float acc = dot2_row64(Wih + ((size_t)l * C + row) * C, curv,
                                   Whh + ((size_t)l * C + row) * C, hl, lane);
            acc = wave_reduce(acc);
            if (lane == 0) {
                float v = acc + bih[l * C + row] + bhh[l * C + row];
                v = fmaxf(v, 0.f);
                hid_new[l * C + row] = v;
                if (l == 2) out[(size_t)t * C + row] = v;   // seq[t]
            }
            grid.sync();
        }
        float* tmp = hid_old; hid_old = hid_new; hid_new = tmp;
    }
}

extern "C" void kernel_launch(void* const* d_in, const int* in_sizes, int n_in,
                              void* d_out, int out_size, void* d_ws, size_t ws_size,
                              hipStream_t stream) {
    const float* x   = (const float*)d_in[0];
    const float* lw0 = (const float*)d_in[1];
    const float* lb0 = (const float*)d_in[2];
    const float* lw1 = (const float*)d_in[3];
    const float* lb1 = (const float*)d_in[4];
    const float* lw2 = (const float*)d_in[5];
    const float* lb2 = (const float*)d_in[6];
    const float* Wih = (const float*)d_in[7];
    const float* bih = (const float*)d_in[8];
    const float* Whh = (const float*)d_in[9];
    const float* bhh = (const float*)d_in[10];
    float* out = (float*)d_out;
    float* wsf = (float*)d_ws;

    void* args[] = {
        (void*)&x, (void*)&lw0, (void*)&lb0, (void*)&lw1, (void*)&lb1,
        (void*)&lw2, (void*)&lb2, (void*)&Wih, (void*)&bih, (void*)&Whh,
        (void*)&bhh, (void*)&out, (void*)&wsf
    };
    hipLaunchCooperativeKernel((const void*)ve_main, dim3(NWG), dim3(TPB),
                               args, 0, stream);
}

// Round 3
// 906.991 us; speedup vs baseline: 5.5301x; 5.5301x over previous
//
#include <hip/hip_runtime.h>
#include <hip/hip_cooperative_groups.h>
#include <math.h>

#define C     1536
#define MA    1536
#define NWG   256
#define TPB   384              // 6 waves/block * 256 blocks = 1536 waves = one per row
#define NEG   0.2f

// workspace layout (32-bit word indices)
#define WS_H0    0             // [C]   MLP hidden 0
#define WS_H1    (C)           // [C]   MLP hidden 1
#define WS_HIDA  (2*C)         // [3*C] RNN state buf A
#define WS_HIDB  (5*C)         // [3*C] RNN state buf B
#define WS_CNUM  (8*C)         // int: step count c (own cache line vs HIDB end)
#define WS_ARR   (8*C + 64)    // unsigned[NWG*16] arrival flags, 64B stride
#define WS_REL   (WS_ARR + NWG*16)  // unsigned release word

__global__ void ve_init(unsigned* w) {
    for (int k = threadIdx.x; k < NWG * 16 + 16; k += blockDim.x)
        __hip_atomic_store(&w[WS_ARR + k], 0u, __ATOMIC_RELAXED, __HIP_MEMORY_SCOPE_AGENT);
}

__device__ __forceinline__ float wave_reduce(float v) {
#pragma unroll
    for (int off = 32; off > 0; off >>= 1) v += __shfl_xor(v, off, 64);
    return v;
}

// streamed 1536-dot over one wave (used only in the 3 MLP head cells)
__device__ __forceinline__ float dot_row64(const float* __restrict__ W,
                                           const float* __restrict__ v, int lane) {
    const float4* W4 = (const float4*)W;
    const float4* v4 = (const float4*)v;
    float acc = 0.f;
#pragma unroll
    for (int j = 0; j < 6; ++j) {
        float4 a = W4[lane + 64 * j];
        float4 b = v4[lane + 64 * j];
        acc = fmaf(a.x, b.x, acc); acc = fmaf(a.y, b.y, acc);
        acc = fmaf(a.z, b.z, acc); acc = fmaf(a.w, b.w, acc);
    }
    return acc;
}

// light grid barrier: no L2 writeback (all shared writes are device-scope atomics)
__device__ __forceinline__ void gbar(unsigned* arr, unsigned* rel, unsigned ep) {
    __syncthreads();
    if (threadIdx.x == 0) {
        asm volatile("s_waitcnt vmcnt(0)" ::: "memory");   // atomics acked at coherence point
        __hip_atomic_store(arr + blockIdx.x * 16, ep, __ATOMIC_RELAXED, __HIP_MEMORY_SCOPE_AGENT);
    }
    if (blockIdx.x == 0) {
        if (threadIdx.x < NWG) {
            while (__hip_atomic_load(arr + threadIdx.x * 16, __ATOMIC_RELAXED,
                                     __HIP_MEMORY_SCOPE_AGENT) < ep)
                __builtin_amdgcn_s_sleep(1);
        }
        __syncthreads();
        if (threadIdx.x == 0)
            __hip_atomic_store(rel, ep, __ATOMIC_RELAXED, __HIP_MEMORY_SCOPE_AGENT);
    }
    if (threadIdx.x == 0) {
        while (__hip_atomic_load(rel, __ATOMIC_RELAXED, __HIP_MEMORY_SCOPE_AGENT) < ep)
            __builtin_amdgcn_s_sleep(1);
        __builtin_amdgcn_fence(__ATOMIC_ACQUIRE, "agent");  // inv L1/L2-nonlocal, no wb
    }
    __syncthreads();
}

__global__ void __launch_bounds__(TPB, 1)
ve_main(const float* __restrict__ x,
        const float* __restrict__ lw0, const float* __restrict__ lb0,
        const float* __restrict__ lw1, const float* __restrict__ lb1,
        const float* __restrict__ lw2, const float* __restrict__ lb2,
        const float* __restrict__ Wih, const float* __restrict__ bih,
        const float* __restrict__ Whh, const float* __restrict__ bhh,
        float* __restrict__ out, float* __restrict__ wsf) {
    unsigned* wsu = (unsigned*)wsf;
    int*      wsi = (int*)wsf;
    unsigned* arr = wsu + WS_ARR;
    unsigned* rel = wsu + WS_REL;
    const int tid  = threadIdx.x;
    const int wg   = blockIdx.x;
    const int wave = tid >> 6;
    const int lane = tid & 63;
    const int row  = wg * 6 + wave;          // this wave's output row
    const int gtid = wg * TPB + tid;
    unsigned ep = 0;

    // ---- preload this wave's 6 weight rows into registers (144 VGPR) ----
    float4 wih[3][6], whh[3][6];
#pragma unroll
    for (int l = 0; l < 3; ++l) {
        const float4* wi = (const float4*)(Wih + ((size_t)l * C + row) * C);
        const float4* wh = (const float4*)(Whh + ((size_t)l * C + row) * C);
#pragma unroll
        for (int j = 0; j < 6; ++j) {
            wih[l][j] = wi[lane + 64 * j];
            whh[l][j] = wh[lane + 64 * j];
        }
    }
    float bsum[3];
#pragma unroll
    for (int l = 0; l < 3; ++l) bsum[l] = bih[l * C + row] + bhh[l * C + row];

    // init hid = [x, 0, 0] via device-scope atomics
    if (gtid < 3 * C) {
        float v = (gtid < C) ? x[gtid] : 0.f;
        __hip_atomic_store(&wsf[WS_HIDA + gtid], v, __ATOMIC_RELAXED, __HIP_MEMORY_SCOPE_AGENT);
    }

    // ---- MLP layer 0 ----
    {
        float acc = wave_reduce(dot_row64(lw0 + (size_t)row * C, x, lane));
        if (lane == 0) {
            float v = acc + lb0[row];
            v = (v > 0.f) ? v : NEG * v;
            __hip_atomic_store(&wsf[WS_H0 + row], v, __ATOMIC_RELAXED, __HIP_MEMORY_SCOPE_AGENT);
        }
    }
    gbar(arr, rel, ++ep);

    // ---- MLP layer 1 ----
    {
        float acc = wave_reduce(dot_row64(lw1 + (size_t)row * C, wsf + WS_H0, lane));
        if (lane == 0) {
            float v = acc + lb1[row];
            v = (v > 0.f) ? v : NEG * v;
            __hip_atomic_store(&wsf[WS_H1 + row], v, __ATOMIC_RELAXED, __HIP_MEMORY_SCOPE_AGENT);
        }
    }
    gbar(arr, rel, ++ep);

    // ---- head: scalar l -> length -> c ----
    if (wg == 0 && wave == 0) {
        float acc = wave_reduce(dot_row64(lw2, wsf + WS_H1, lane));
        if (lane == 0) {
            float l = acc + lb2[0];
            float length = fminf(fabsf(l), 0.9999f);
            __hip_atomic_store(&out[(size_t)MA * C], length, __ATOMIC_RELAXED, __HIP_MEMORY_SCOPE_AGENT);
            __hip_atomic_store(&wsi[WS_CNUM], (int)floorf(length * (float)MA) + 1,
                               __ATOMIC_RELAXED, __HIP_MEMORY_SCOPE_AGENT);
        }
    }
    gbar(arr, rel, ++ep);
    const int csteps = wsi[WS_CNUM];

    // ---- RNN: csteps timesteps x 3 layers, weights in registers ----
    float* hid_old = wsf + WS_HIDA;   // [x, 0, 0]
    float* hid_new = wsf + WS_HIDB;
    for (int t = 0; t < csteps; ++t) {
#pragma unroll
        for (int l = 0; l < 3; ++l) {
            const float4* cv4 = (const float4*)((l == 0) ? (hid_old + 2 * C)
                                                         : (hid_new + (l - 1) * C));
            const float4* hv4 = (const float4*)(hid_old + l * C);
            float acc = 0.f;
#pragma unroll
            for (int j = 0; j < 6; ++j) {
                float4 b = cv4[lane + 64 * j];
                float4 a = wih[l][j];
                acc = fmaf(a.x, b.x, acc); acc = fmaf(a.y, b.y, acc);
                acc = fmaf(a.z, b.z, acc); acc = fmaf(a.w, b.w, acc);
                float4 d = hv4[lane + 64 * j];
                float4 e = whh[l][j];
                acc = fmaf(e.x, d.x, acc); acc = fmaf(e.y, d.y, acc);
                acc = fmaf(e.z, d.z, acc); acc = fmaf(e.w, d.w, acc);
            }
            acc = wave_reduce(acc);
            if (lane == 0) {
                float v = fmaxf(acc + bsum[l], 0.f);
                __hip_atomic_store(&hid_new[l * C + row], v, __ATOMIC_RELAXED,
                                   __HIP_MEMORY_SCOPE_AGENT);
                if (l == 2)
                    __hip_atomic_store(&out[(size_t)t * C + row], v, __ATOMIC_RELAXED,
                                       __HIP_MEMORY_SCOPE_AGENT);
            }
            gbar(arr, rel, ++ep);
        }
        float* tmp = hid_old; hid_old = hid_new; hid_new = tmp;
    }
}

extern "C" void kernel_launch(void* const* d_in, const int* in_sizes, int n_in,
                              void* d_out, int out_size, void* d_ws, size_t ws_size,
                              hipStream_t stream) {
    const float* x   = (const float*)d_in[0];
    const float* lw0 = (const float*)d_in[1];
    const float* lb0 = (const float*)d_in[2];
    const float* lw1 = (const float*)d_in[3];
    const float* lb1 = (const float*)d_in[4];
    const float* lw2 = (const float*)d_in[5];
    const float* lb2 = (const float*)d_in[6];
    const float* Wih = (const float*)d_in[7];
    const float* bih = (const float*)d_in[8];
    const float* Whh = (const float*)d_in[9];
    const float* bhh = (const float*)d_in[10];
    float* out = (float*)d_out;
    float* wsf = (float*)d_ws;

    // zero seq region (rows >= c must be 0); length slot overwritten by kernel
    hipMemsetAsync(d_out, 0, (size_t)out_size * sizeof(float), stream);
    hipLaunchKernelGGL(ve_init, dim3(1), dim3(256), 0, stream, (unsigned*)d_ws);

    void* args[] = {
        (void*)&x, (void*)&lw0, (void*)&lb0, (void*)&lw1, (void*)&lb1,
        (void*)&lw2, (void*)&lb2, (void*)&Wih, (void*)&bih, (void*)&Whh,
        (void*)&bhh, (void*)&out, (void*)&wsf
    };
    hipLaunchCooperativeKernel((const void*)ve_main, dim3(NWG), dim3(TPB),
                               args, 0, stream);
}